// Round 6
// baseline (500.960 us; speedup 1.0000x reference)
//
#include <hip/hip_runtime.h>

#define NCLS 88
#define DHW (96 * 96 * 96)            // 884736
#define TPB 256                       // 4 waves = 2 wave-pairs
#define HALF_CLS 44                   // classes per wave in a pair
#define NCH 11                        // chunks of 4 classes per half
#define VPJ 256                       // voxels per block per j-iter (2 pairs x 64 lanes x 2)
#define NJ 2                          // j-iterations
#define VOX_PER_BLOCK (VPJ * NJ)      // 512
#define BLOCKS_PER_B (DHW / VOX_PER_BLOCK)   // 1728, exact
#define SLOTS 32
#define SMOOTH 1e-5f
#define WS_PER_SLOT 529
// ws layout per slot: [0..176) inter[b*88+c] | [176..352) pred_o | [352..528) cnt | [528] ce

typedef __fp16 h2 __attribute__((ext_vector_type(2)));
typedef float f2 __attribute__((ext_vector_type(2)));
union H2I { h2 h; int i; };

__device__ __forceinline__ float wave_reduce_sum(float v) {
#pragma unroll
    for (int i = 1; i < 64; i <<= 1)
        v += __shfl_xor(v, i, 64);
    return v;
}

__device__ __forceinline__ h2 wave_reduce_h2(h2 v) {
#pragma unroll
    for (int i = 1; i < 64; i <<= 1) {
        H2I u; u.h = v;
        u.i = __shfl_xor(u.i, i, 64);
        v = v + u.h;                   // v_pk_add_f16
    }
    return v;
}

__global__ __launch_bounds__(TPB, 4)
void seg_loss_main(const float* __restrict__ pred, const int* __restrict__ tgt,
                   float* __restrict__ ws) {
    __shared__ float s_inter[NCLS];
    __shared__ float s_pred[NCLS];
    __shared__ float s_cnt[NCLS];
    __shared__ float s_ce;
    __shared__ float4 s_ex[2][2][2][64];   // [j-parity][pair][half][lane]

    const int tid  = threadIdx.x;
    const int lane = tid & 63;
    const int wave = tid >> 6;
    const int pair = wave >> 1;
    const int half = wave & 1;
    const int b    = blockIdx.x / BLOCKS_PER_B;
    const int base = (blockIdx.x % BLOCKS_PER_B) * VOX_PER_BLOCK;
    const int cls0 = half * HALF_CLS;
    const float* pb = pred + (size_t)b * NCLS * DHW + (size_t)cls0 * DHW;
    const int*   tb = tgt  + (size_t)b * DHW;

    if (tid < NCLS) { s_inter[tid] = 0.f; s_pred[tid] = 0.f; s_cnt[tid] = 0.f; }
    if (tid == 0) s_ce = 0.f;
    __syncthreads();

    h2 acc[NCH * 2];                   // my half's per-class sum of p^2
#pragma unroll
    for (int i = 0; i < NCH * 2; ++i) acc[i] = (h2){(__fp16)0.f, (__fp16)0.f};
    float ce_acc = 0.f;

    for (int j = 0; j < NJ; ++j) {
        const int vox = base + j * VPJ + pair * 128 + lane * 2;
        const int2 t2 = *(const int2*)(tb + vox);
        const bool val0 = (t2.x != -1), val1 = (t2.y != -1);
        const int tc0 = val0 ? t2.x : 0;
        const int tc1 = val1 ? t2.y : 0;
        const float vf0 = val0 ? 1.f : 0.f;
        const float vf1 = val1 ? 1.f : 0.f;
        const float* p = pb + vox;

        // ---- pass A: 44 classes, float2 (2 voxels) per load, fp8-packed exps ----
        float sA0 = 0.f, sB0 = 0.f, sA1 = 0.f, sB1 = 0.f;
        float et0a = 0.f, et0b = 0.f, et1a = 0.f, et1b = 0.f;
        int efA[NCH], efB[NCH];
#pragma unroll
        for (int q = 0; q < NCH; ++q) {
            float2 x0 = *(const float2*)(p + (size_t)(q * 4 + 0) * DHW);
            float2 x1 = *(const float2*)(p + (size_t)(q * 4 + 1) * DHW);
            float2 x2 = *(const float2*)(p + (size_t)(q * 4 + 2) * DHW);
            float2 x3 = *(const float2*)(p + (size_t)(q * 4 + 3) * DHW);
            const float e00 = __expf(x0.x * vf0), e01 = __expf(x1.x * vf0);
            const float e02 = __expf(x2.x * vf0), e03 = __expf(x3.x * vf0);
            const float e10 = __expf(x0.y * vf1), e11 = __expf(x1.y * vf1);
            const float e12 = __expf(x2.y * vf1), e13 = __expf(x3.y * vf1);
            sA0 += e00 + e01;  sB0 += e02 + e03;
            sA1 += e10 + e11;  sB1 += e12 + e13;
            const int cb = cls0 + q * 4;
            et0a = (cb + 0 == tc0) ? e00 : et0a;
            et0b = (cb + 1 == tc0) ? e01 : et0b;
            et0a = (cb + 2 == tc0) ? e02 : et0a;
            et0b = (cb + 3 == tc0) ? e03 : et0b;
            et1a = (cb + 0 == tc1) ? e10 : et1a;
            et1b = (cb + 1 == tc1) ? e11 : et1b;
            et1a = (cb + 2 == tc1) ? e12 : et1a;
            et1b = (cb + 3 == tc1) ? e13 : et1b;
            int lo0 = __builtin_amdgcn_cvt_pk_fp8_f32(e00, e01, 0, false);
            efA[q] = __builtin_amdgcn_cvt_pk_fp8_f32(e02, e03, lo0, true);
            int lo1 = __builtin_amdgcn_cvt_pk_fp8_f32(e10, e11, 0, false);
            efB[q] = __builtin_amdgcn_cvt_pk_fp8_f32(e12, e13, lo1, true);
        }
        const float s1h0 = sA0 + sB0, s1h1 = sA1 + sB1;
        const float etm0 = fmaxf(et0a, et0b), etm1 = fmaxf(et1a, et1b);

        // ---- cross-wave exchange (one barrier, j-parity double buffer) ----
        s_ex[j & 1][pair][half][lane] = make_float4(s1h0, s1h1, etm0, etm1);
        __syncthreads();
        const float4 oth = s_ex[j & 1][pair][half ^ 1][lane];
        const float s1_0 = s1h0 + oth.x, s1_1 = s1h1 + oth.y;
        const float et0 = etm0 + oth.z, et1 = etm1 + oth.w;
        const float inv0 = 1.f / s1_0, inv1 = 1.f / s1_1;

        // ---- CE + inter/cnt by owner half ----
        const bool own0 = (tc0 >= cls0) && (tc0 < cls0 + HALF_CLS);
        const bool own1 = (tc1 >= cls0) && (tc1 < cls0 + HALF_CLS);
        const float pt0 = et0 * inv0, pt1 = et1 * inv1;
        if (val0 && own0) {
            ce_acc -= __logf(pt0);
            atomicAdd(&s_inter[tc0], pt0);
            atomicAdd(&s_cnt[tc0], 1.f);
        }
        if (val1 && own1) {
            ce_acc -= __logf(pt1);
            atomicAdd(&s_inter[tc1], pt1);
            atomicAdd(&s_cnt[tc1], 1.f);
        }

        // ---- pass B: p^2 into fp16 per-class accumulators, zero shuffles ----
#pragma unroll
        for (int q = 0; q < NCH; ++q) {
            f2 a = __builtin_amdgcn_cvt_pk_f32_fp8(efA[q], false);  // v0: c0,c1
            f2 bb = __builtin_amdgcn_cvt_pk_f32_fp8(efA[q], true);  // v0: c2,c3
            f2 c = __builtin_amdgcn_cvt_pk_f32_fp8(efB[q], false);  // v1: c0,c1
            f2 d = __builtin_amdgcn_cvt_pk_f32_fp8(efB[q], true);   // v1: c2,c3
            h2 h0 = __builtin_amdgcn_cvt_pkrtz(a.x * inv0, a.y * inv0);
            h2 h1 = __builtin_amdgcn_cvt_pkrtz(bb.x * inv0, bb.y * inv0);
            h2 hv0 = __builtin_amdgcn_cvt_pkrtz(c.x * inv1, c.y * inv1);
            h2 hv1 = __builtin_amdgcn_cvt_pkrtz(d.x * inv1, d.y * inv1);
            acc[2 * q]     += h0 * h0 + hv0 * hv0;
            acc[2 * q + 1] += h1 * h1 + hv1 * hv1;
        }
    }

    // ---- one wave-reduce per class-pair per thread lifetime ----
#pragma unroll
    for (int i = 0; i < NCH * 2; ++i) {
        h2 r = wave_reduce_h2(acc[i]);
        if (lane == 0) {
            atomicAdd(&s_pred[cls0 + 2 * i],     (float)r.x);
            atomicAdd(&s_pred[cls0 + 2 * i + 1], (float)r.y);
        }
    }
    ce_acc = wave_reduce_sum(ce_acc);
    if (lane == 0) atomicAdd(&s_ce, ce_acc);

    __syncthreads();

    // ---- block partials -> striped global slots ----
    float* wsl = ws + (size_t)(blockIdx.x & (SLOTS - 1)) * WS_PER_SLOT;
    if (tid < NCLS) {
        atomicAdd(&wsl[0 * 176 + b * NCLS + tid], s_inter[tid]);
        atomicAdd(&wsl[1 * 176 + b * NCLS + tid], s_pred[tid]);
        atomicAdd(&wsl[2 * 176 + b * NCLS + tid], s_cnt[tid]);
    }
    if (tid == 0) atomicAdd(&wsl[528], s_ce);
}

__global__ __launch_bounds__(TPB)
void seg_loss_final(const float* __restrict__ ws, float* __restrict__ out) {
    const int tid = threadIdx.x;
    float dice = 0.f, cnt = 0.f;
    if (tid < 2 * NCLS) {
        float I = 0.f, P = 0.f, G = 0.f;
        for (int s = 0; s < SLOTS; ++s) {
            const float* w = ws + (size_t)s * WS_PER_SLOT;
            I += w[tid]; P += w[176 + tid]; G += w[352 + tid];
        }
        dice = 1.f - (2.f * I + SMOOTH) / (G + P + SMOOTH);
        cnt  = G;
    }
    float ce_s = 0.f;
    if (tid < SLOTS) ce_s = ws[(size_t)tid * WS_PER_SLOT + 528];

    dice = wave_reduce_sum(dice);
    cnt  = wave_reduce_sum(cnt);
    ce_s = wave_reduce_sum(ce_s);

    __shared__ float sd[4], sc2[4], se[4];
    const int w = tid >> 6, l = tid & 63;
    if (l == 0) { sd[w] = dice; sc2[w] = cnt; se[w] = ce_s; }
    __syncthreads();
    if (tid == 0) {
        const float D  = sd[0] + sd[1] + sd[2] + sd[3];
        const float Cn = sc2[0] + sc2[1] + sc2[2] + sc2[3];
        const float CE = (se[0] + se[1] + se[2] + se[3]) / fmaxf(Cn, 1.0f);
        out[0] = 0.4f * CE + 0.6f * (D / 176.f);
    }
}

extern "C" void kernel_launch(void* const* d_in, const int* in_sizes, int n_in,
                              void* d_out, int out_size, void* d_ws, size_t ws_size,
                              hipStream_t stream) {
    const float* pred = (const float*)d_in[0];
    const int*   tgt  = (const int*)d_in[1];
    float* ws = (float*)d_ws;

    (void)hipMemsetAsync(d_ws, 0, SLOTS * WS_PER_SLOT * sizeof(float), stream);
    seg_loss_main<<<2 * BLOCKS_PER_B, TPB, 0, stream>>>(pred, tgt, ws);
    seg_loss_final<<<1, TPB, 0, stream>>>(ws, (float*)d_out);
}

// Round 7
// 161.024 us; speedup vs baseline: 3.1111x; 3.1111x over previous
//
#include <hip/hip_runtime.h>

#define NCLS 88
#define DHW (96 * 96 * 96)            // 884736
#define TPB 256                       // 4 waves = 2 wave-pairs
#define HALF_CLS 44                   // classes per wave in a pair
#define NCH 11                        // chunks of 4 classes per half
#define VPJ 256                       // voxels per block per j-iter
#define NJ 2
#define VOX_PER_BLOCK (VPJ * NJ)      // 512
#define BLOCKS_PER_B (DHW / VOX_PER_BLOCK)   // 1728, exact
#define SLOTS 32
#define SMOOTH 1e-5f
#define WS_PER_SLOT 529
// ws layout per slot: [0..176) inter[b*88+c] | [176..352) pred_o | [352..528) cnt | [528] ce

typedef __fp16 h2 __attribute__((ext_vector_type(2)));
typedef float f2 __attribute__((ext_vector_type(2)));
union H2I { h2 h; int i; };

__device__ __forceinline__ float wave_reduce_sum(float v) {
#pragma unroll
    for (int i = 1; i < 64; i <<= 1)
        v += __shfl_xor(v, i, 64);
    return v;
}

__device__ __forceinline__ h2 wave_reduce_h2(h2 v) {
#pragma unroll
    for (int i = 1; i < 64; i <<= 1) {
        H2I u; u.h = v;
        u.i = __shfl_xor(u.i, i, 64);
        v = v + u.h;                   // v_pk_add_f16
    }
    return v;
}

// NOTE: no min-waves arg — __launch_bounds__(TPB, 4) forced a 64-VGPR
// allocation and ~1.5 GB of spill traffic in R4/R6. Plain bound lands
// ~100-128 VGPR, 4 waves/SIMD, zero scratch.
__global__ __launch_bounds__(TPB)
void seg_loss_main(const float* __restrict__ pred, const int* __restrict__ tgt,
                   float* __restrict__ ws) {
    __shared__ float s_inter[NCLS];
    __shared__ float s_pred[NCLS];
    __shared__ float s_cnt[NCLS];
    __shared__ float s_ce;
    // stride-1 float arrays: conflict-free (2 lanes/bank is free)
    __shared__ float s_s1a[2][2][2][64];   // [j-parity][pair][half][lane] partial s1 vox0
    __shared__ float s_s1b[2][2][2][64];   // vox1
    __shared__ float s_eta[2][2][2][64];   // e_tgt vox0
    __shared__ float s_etb[2][2][2][64];   // e_tgt vox1

    const int tid  = threadIdx.x;
    const int lane = tid & 63;
    const int wave = tid >> 6;
    const int pair = wave >> 1;
    const int half = wave & 1;
    const int b    = blockIdx.x / BLOCKS_PER_B;
    const int base = (blockIdx.x % BLOCKS_PER_B) * VOX_PER_BLOCK;
    const int cls0 = half * HALF_CLS;
    const float* pb = pred + (size_t)b * NCLS * DHW + (size_t)cls0 * DHW;
    const int*   tb = tgt  + (size_t)b * DHW;

    if (tid < NCLS) { s_inter[tid] = 0.f; s_pred[tid] = 0.f; s_cnt[tid] = 0.f; }
    if (tid == 0) s_ce = 0.f;
    __syncthreads();

    h2 acc[NCH * 2];                   // my half's per-class sum of p^2
#pragma unroll
    for (int i = 0; i < NCH * 2; ++i) acc[i] = (h2){(__fp16)0.f, (__fp16)0.f};
    float ce_acc = 0.f;

    for (int j = 0; j < NJ; ++j) {
        const int vox = base + j * VPJ + pair * 128 + lane * 2;
        const int2 t2 = *(const int2*)(tb + vox);
        const bool val0 = (t2.x != -1), val1 = (t2.y != -1);
        const int tc0 = val0 ? t2.x : 0;
        const int tc1 = val1 ? t2.y : 0;
        const float vf0 = val0 ? 1.f : 0.f;
        const float vf1 = val1 ? 1.f : 0.f;
        const float* p = pb + vox;

        // ---- pass A: 44 classes, float2 (2 voxels) per load, fp8-packed exps ----
        float sA0 = 0.f, sB0 = 0.f, sA1 = 0.f, sB1 = 0.f;
        float et0a = 0.f, et0b = 0.f, et1a = 0.f, et1b = 0.f;
        int efA[NCH], efB[NCH];
#pragma unroll
        for (int q = 0; q < NCH; ++q) {
            float2 x0 = *(const float2*)(p + (size_t)(q * 4 + 0) * DHW);
            float2 x1 = *(const float2*)(p + (size_t)(q * 4 + 1) * DHW);
            float2 x2 = *(const float2*)(p + (size_t)(q * 4 + 2) * DHW);
            float2 x3 = *(const float2*)(p + (size_t)(q * 4 + 3) * DHW);
            const float e00 = __expf(x0.x * vf0), e01 = __expf(x1.x * vf0);
            const float e02 = __expf(x2.x * vf0), e03 = __expf(x3.x * vf0);
            const float e10 = __expf(x0.y * vf1), e11 = __expf(x1.y * vf1);
            const float e12 = __expf(x2.y * vf1), e13 = __expf(x3.y * vf1);
            sA0 += e00 + e01;  sB0 += e02 + e03;
            sA1 += e10 + e11;  sB1 += e12 + e13;
            const int cb = cls0 + q * 4;
            et0a = (cb + 0 == tc0) ? e00 : et0a;
            et0b = (cb + 1 == tc0) ? e01 : et0b;
            et0a = (cb + 2 == tc0) ? e02 : et0a;
            et0b = (cb + 3 == tc0) ? e03 : et0b;
            et1a = (cb + 0 == tc1) ? e10 : et1a;
            et1b = (cb + 1 == tc1) ? e11 : et1b;
            et1a = (cb + 2 == tc1) ? e12 : et1a;
            et1b = (cb + 3 == tc1) ? e13 : et1b;
            int lo0 = __builtin_amdgcn_cvt_pk_fp8_f32(e00, e01, 0, false);
            efA[q] = __builtin_amdgcn_cvt_pk_fp8_f32(e02, e03, lo0, true);
            int lo1 = __builtin_amdgcn_cvt_pk_fp8_f32(e10, e11, 0, false);
            efB[q] = __builtin_amdgcn_cvt_pk_fp8_f32(e12, e13, lo1, true);
        }
        const float s1h0 = sA0 + sB0, s1h1 = sA1 + sB1;
        const float etm0 = fmaxf(et0a, et0b), etm1 = fmaxf(et1a, et1b);

        // ---- cross-wave exchange (one barrier, j-parity double buffer) ----
        s_s1a[j & 1][pair][half][lane] = s1h0;
        s_s1b[j & 1][pair][half][lane] = s1h1;
        s_eta[j & 1][pair][half][lane] = etm0;
        s_etb[j & 1][pair][half][lane] = etm1;
        __syncthreads();
        const float s1_0 = s1h0 + s_s1a[j & 1][pair][half ^ 1][lane];
        const float s1_1 = s1h1 + s_s1b[j & 1][pair][half ^ 1][lane];
        const float et0  = etm0 + s_eta[j & 1][pair][half ^ 1][lane];
        const float et1  = etm1 + s_etb[j & 1][pair][half ^ 1][lane];
        const float inv0 = 1.f / s1_0, inv1 = 1.f / s1_1;

        // ---- CE + inter/cnt by owner half ----
        const bool own0 = (tc0 >= cls0) && (tc0 < cls0 + HALF_CLS);
        const bool own1 = (tc1 >= cls0) && (tc1 < cls0 + HALF_CLS);
        const float pt0 = et0 * inv0, pt1 = et1 * inv1;
        if (val0 && own0) {
            ce_acc -= __logf(pt0);
            atomicAdd(&s_inter[tc0], pt0);
            atomicAdd(&s_cnt[tc0], 1.f);
        }
        if (val1 && own1) {
            ce_acc -= __logf(pt1);
            atomicAdd(&s_inter[tc1], pt1);
            atomicAdd(&s_cnt[tc1], 1.f);
        }

        // ---- pass B: p^2 into fp16 per-class accumulators, zero shuffles ----
#pragma unroll
        for (int q = 0; q < NCH; ++q) {
            f2 a  = __builtin_amdgcn_cvt_pk_f32_fp8(efA[q], false);  // v0: c0,c1
            f2 bb = __builtin_amdgcn_cvt_pk_f32_fp8(efA[q], true);   // v0: c2,c3
            f2 c  = __builtin_amdgcn_cvt_pk_f32_fp8(efB[q], false);  // v1: c0,c1
            f2 d  = __builtin_amdgcn_cvt_pk_f32_fp8(efB[q], true);   // v1: c2,c3
            h2 h0  = __builtin_amdgcn_cvt_pkrtz(a.x * inv0, a.y * inv0);
            h2 h1  = __builtin_amdgcn_cvt_pkrtz(bb.x * inv0, bb.y * inv0);
            h2 hv0 = __builtin_amdgcn_cvt_pkrtz(c.x * inv1, c.y * inv1);
            h2 hv1 = __builtin_amdgcn_cvt_pkrtz(d.x * inv1, d.y * inv1);
            acc[2 * q]     += h0 * h0 + hv0 * hv0;
            acc[2 * q + 1] += h1 * h1 + hv1 * hv1;
        }
    }

    // ---- one wave-reduce per class-pair per thread lifetime ----
#pragma unroll
    for (int i = 0; i < NCH * 2; ++i) {
        h2 r = wave_reduce_h2(acc[i]);
        if (lane == 0) {
            atomicAdd(&s_pred[cls0 + 2 * i],     (float)r.x);
            atomicAdd(&s_pred[cls0 + 2 * i + 1], (float)r.y);
        }
    }
    ce_acc = wave_reduce_sum(ce_acc);
    if (lane == 0) atomicAdd(&s_ce, ce_acc);

    __syncthreads();

    // ---- block partials -> striped global slots ----
    float* wsl = ws + (size_t)(blockIdx.x & (SLOTS - 1)) * WS_PER_SLOT;
    if (tid < NCLS) {
        atomicAdd(&wsl[0 * 176 + b * NCLS + tid], s_inter[tid]);
        atomicAdd(&wsl[1 * 176 + b * NCLS + tid], s_pred[tid]);
        atomicAdd(&wsl[2 * 176 + b * NCLS + tid], s_cnt[tid]);
    }
    if (tid == 0) atomicAdd(&wsl[528], s_ce);
}

__global__ __launch_bounds__(TPB)
void seg_loss_final(const float* __restrict__ ws, float* __restrict__ out) {
    const int tid = threadIdx.x;
    float dice = 0.f, cnt = 0.f;
    if (tid < 2 * NCLS) {
        float I = 0.f, P = 0.f, G = 0.f;
        for (int s = 0; s < SLOTS; ++s) {
            const float* w = ws + (size_t)s * WS_PER_SLOT;
            I += w[tid]; P += w[176 + tid]; G += w[352 + tid];
        }
        dice = 1.f - (2.f * I + SMOOTH) / (G + P + SMOOTH);
        cnt  = G;
    }
    float ce_s = 0.f;
    if (tid < SLOTS) ce_s = ws[(size_t)tid * WS_PER_SLOT + 528];

    dice = wave_reduce_sum(dice);
    cnt  = wave_reduce_sum(cnt);
    ce_s = wave_reduce_sum(ce_s);

    __shared__ float sd[4], sc2[4], se[4];
    const int w = tid >> 6, l = tid & 63;
    if (l == 0) { sd[w] = dice; sc2[w] = cnt; se[w] = ce_s; }
    __syncthreads();
    if (tid == 0) {
        const float D  = sd[0] + sd[1] + sd[2] + sd[3];
        const float Cn = sc2[0] + sc2[1] + sc2[2] + sc2[3];
        const float CE = (se[0] + se[1] + se[2] + se[3]) / fmaxf(Cn, 1.0f);
        out[0] = 0.4f * CE + 0.6f * (D / 176.f);
    }
}

extern "C" void kernel_launch(void* const* d_in, const int* in_sizes, int n_in,
                              void* d_out, int out_size, void* d_ws, size_t ws_size,
                              hipStream_t stream) {
    const float* pred = (const float*)d_in[0];
    const int*   tgt  = (const int*)d_in[1];
    float* ws = (float*)d_ws;

    (void)hipMemsetAsync(d_ws, 0, SLOTS * WS_PER_SLOT * sizeof(float), stream);
    seg_loss_main<<<2 * BLOCKS_PER_B, TPB, 0, stream>>>(pred, tgt, ws);
    seg_loss_final<<<1, TPB, 0, stream>>>(ws, (float*)d_out);
}

// Round 8
// 140.598 us; speedup vs baseline: 3.5631x; 1.1453x over previous
//
#include <hip/hip_runtime.h>

#define NCLS 88
#define DHW (96 * 96 * 96)            // 884736
#define TPB 256                       // 4 waves, 4-way class split
#define CPW 22                        // classes per wave
#define VPJ 256                       // voxels per block per j-iter (64 lanes x 4)
#define NJ 2
#define VOX_PER_BLOCK (VPJ * NJ)      // 512
#define BLOCKS_PER_B (DHW / VOX_PER_BLOCK)   // 1728, exact
#define SLOTS 32
#define SMOOTH 1e-5f
#define WS_PER_SLOT 529
// ws layout per slot: [0..176) inter[b*88+c] | [176..352) pred_o | [352..528) cnt | [528] ce

typedef __fp16 h2 __attribute__((ext_vector_type(2)));
typedef float f2 __attribute__((ext_vector_type(2)));
union H2I { h2 h; int i; };

__device__ __forceinline__ float wave_reduce_sum(float v) {
#pragma unroll
    for (int i = 1; i < 64; i <<= 1)
        v += __shfl_xor(v, i, 64);
    return v;
}

__device__ __forceinline__ h2 wave_reduce_h2(h2 v) {
#pragma unroll
    for (int i = 1; i < 64; i <<= 1) {
        H2I u; u.h = v;
        u.i = __shfl_xor(u.i, i, 64);
        v = v + u.h;                   // v_pk_add_f16
    }
    return v;
}

// NOTE: no min-waves arg — __launch_bounds__(TPB,4) forced 64-VGPR + spill
// (R4/R6, ~1.5 GB scratch traffic). Plain bound: ~90 VGPR, 5 waves/SIMD, 0 scratch.
__global__ __launch_bounds__(TPB)
void seg_loss_main(const float* __restrict__ pred, const int* __restrict__ tgt,
                   float* __restrict__ ws) {
    __shared__ float s_inter[NCLS];
    __shared__ float s_pred[NCLS];
    __shared__ float s_cnt[NCLS];
    __shared__ float s_ce;
    __shared__ float2 s_ex[NJ][4][4][64];  // [j][wave][vox][lane] = {s1_part, et_part}

    const int tid  = threadIdx.x;
    const int lane = tid & 63;
    const int wave = tid >> 6;
    const int b    = blockIdx.x / BLOCKS_PER_B;
    const int base = (blockIdx.x % BLOCKS_PER_B) * VOX_PER_BLOCK;
    const int cls0 = wave * CPW;
    const float* pb = pred + (size_t)b * NCLS * DHW + (size_t)cls0 * DHW;
    const int*   tb = tgt  + (size_t)b * DHW;

    if (tid < NCLS) { s_inter[tid] = 0.f; s_pred[tid] = 0.f; s_cnt[tid] = 0.f; }
    if (tid == 0) s_ce = 0.f;
    __syncthreads();

    h2 acc[CPW / 2];                   // my 22 classes' sum of p^2 (fp16 pairs)
#pragma unroll
    for (int i = 0; i < CPW / 2; ++i) acc[i] = (h2){(__fp16)0.f, (__fp16)0.f};
    float ce_acc = 0.f;

    for (int j = 0; j < NJ; ++j) {
        const int vox = base + j * VPJ + lane * 4;
        const int4 t4 = *(const int4*)(tb + vox);
        const int tv[4] = { t4.x, t4.y, t4.z, t4.w };
        bool  val[4]; int tc[4]; float vf[4];
#pragma unroll
        for (int v = 0; v < 4; ++v) {
            val[v] = (tv[v] != -1);
            tc[v]  = val[v] ? tv[v] : 0;
            vf[v]  = val[v] ? 1.f : 0.f;
        }
        const float* p = pb + vox;

        // ---- pass A: 22 classes x float4 (4 voxels/lane), fp8-packed exps ----
        float sA[4] = {0,0,0,0}, sB[4] = {0,0,0,0};
        float eta[4] = {0,0,0,0}, etb[4] = {0,0,0,0};
        int ef[CPW];
#pragma unroll
        for (int c = 0; c < CPW; ++c) {
            const float4 x = *(const float4*)(p + (size_t)c * DHW);
            const float e0 = __expf(x.x * vf[0]);
            const float e1 = __expf(x.y * vf[1]);
            const float e2 = __expf(x.z * vf[2]);
            const float e3 = __expf(x.w * vf[3]);
            const int cc = cls0 + c;
            if (c & 1) {
                sB[0] += e0; sB[1] += e1; sB[2] += e2; sB[3] += e3;
                etb[0] = (cc == tc[0]) ? e0 : etb[0];
                etb[1] = (cc == tc[1]) ? e1 : etb[1];
                etb[2] = (cc == tc[2]) ? e2 : etb[2];
                etb[3] = (cc == tc[3]) ? e3 : etb[3];
            } else {
                sA[0] += e0; sA[1] += e1; sA[2] += e2; sA[3] += e3;
                eta[0] = (cc == tc[0]) ? e0 : eta[0];
                eta[1] = (cc == tc[1]) ? e1 : eta[1];
                eta[2] = (cc == tc[2]) ? e2 : eta[2];
                eta[3] = (cc == tc[3]) ? e3 : eta[3];
            }
            const int lo = __builtin_amdgcn_cvt_pk_fp8_f32(e0, e1, 0, false);
            ef[c] = __builtin_amdgcn_cvt_pk_fp8_f32(e2, e3, lo, true);
        }

        // ---- cross-wave exchange: 4 partials per voxel, one barrier ----
#pragma unroll
        for (int v = 0; v < 4; ++v)
            s_ex[j][wave][v][lane] = make_float2(sA[v] + sB[v], eta[v] + etb[v]);
        __syncthreads();

        float inv[4], pt[4];
#pragma unroll
        for (int v = 0; v < 4; ++v) {
            const float2 q0 = s_ex[j][0][v][lane];
            const float2 q1 = s_ex[j][1][v][lane];
            const float2 q2 = s_ex[j][2][v][lane];
            const float2 q3 = s_ex[j][3][v][lane];
            const float s1 = (q0.x + q1.x) + (q2.x + q3.x);
            const float et = (q0.y + q1.y) + (q2.y + q3.y);
            inv[v] = 1.f / s1;
            pt[v]  = et * inv[v];
        }

        // ---- CE + inter/cnt, owner wave only ----
#pragma unroll
        for (int v = 0; v < 4; ++v) {
            const bool own = (tc[v] >= cls0) && (tc[v] < cls0 + CPW);
            if (val[v] && own) {
                ce_acc -= __logf(pt[v]);
                atomicAdd(&s_inter[tc[v]], pt[v]);
                atomicAdd(&s_cnt[tc[v]], 1.f);
            }
        }

        // ---- pass B: p^2 per class over 4 voxels, fp16 class-pair accumulators ----
#pragma unroll
        for (int q = 0; q < CPW / 2; ++q) {
            const f2 lo0 = __builtin_amdgcn_cvt_pk_f32_fp8(ef[2 * q],     false);
            const f2 hi0 = __builtin_amdgcn_cvt_pk_f32_fp8(ef[2 * q],     true);
            const f2 lo1 = __builtin_amdgcn_cvt_pk_f32_fp8(ef[2 * q + 1], false);
            const f2 hi1 = __builtin_amdgcn_cvt_pk_f32_fp8(ef[2 * q + 1], true);
            const float a0 = lo0.x * inv[0], a1 = lo0.y * inv[1];
            const float a2 = hi0.x * inv[2], a3 = hi0.y * inv[3];
            const float b0 = lo1.x * inv[0], b1 = lo1.y * inv[1];
            const float b2 = hi1.x * inv[2], b3 = hi1.y * inv[3];
            const float sq0 = (a0 * a0 + a1 * a1) + (a2 * a2 + a3 * a3);
            const float sq1 = (b0 * b0 + b1 * b1) + (b2 * b2 + b3 * b3);
            acc[q] += __builtin_amdgcn_cvt_pkrtz(sq0, sq1);
        }
    }

    // ---- one wave-reduce per class-pair per thread lifetime ----
#pragma unroll
    for (int i = 0; i < CPW / 2; ++i) {
        h2 r = wave_reduce_h2(acc[i]);
        if (lane == 0) {
            // this block's only contributor to these classes (class split) -> plain add
            s_pred[cls0 + 2 * i]     += (float)r.x;
            s_pred[cls0 + 2 * i + 1] += (float)r.y;
        }
    }
    ce_acc = wave_reduce_sum(ce_acc);
    if (lane == 0) atomicAdd(&s_ce, ce_acc);

    __syncthreads();

    // ---- block partials -> striped global slots ----
    float* wsl = ws + (size_t)(blockIdx.x & (SLOTS - 1)) * WS_PER_SLOT;
    if (tid < NCLS) {
        atomicAdd(&wsl[0 * 176 + b * NCLS + tid], s_inter[tid]);
        atomicAdd(&wsl[1 * 176 + b * NCLS + tid], s_pred[tid]);
        atomicAdd(&wsl[2 * 176 + b * NCLS + tid], s_cnt[tid]);
    }
    if (tid == 0) atomicAdd(&wsl[528], s_ce);
}

__global__ __launch_bounds__(TPB)
void seg_loss_final(const float* __restrict__ ws, float* __restrict__ out) {
    const int tid = threadIdx.x;
    float dice = 0.f, cnt = 0.f;
    if (tid < 2 * NCLS) {
        float I = 0.f, P = 0.f, G = 0.f;
        for (int s = 0; s < SLOTS; ++s) {
            const float* w = ws + (size_t)s * WS_PER_SLOT;
            I += w[tid]; P += w[176 + tid]; G += w[352 + tid];
        }
        dice = 1.f - (2.f * I + SMOOTH) / (G + P + SMOOTH);
        cnt  = G;
    }
    float ce_s = 0.f;
    if (tid < SLOTS) ce_s = ws[(size_t)tid * WS_PER_SLOT + 528];

    dice = wave_reduce_sum(dice);
    cnt  = wave_reduce_sum(cnt);
    ce_s = wave_reduce_sum(ce_s);

    __shared__ float sd[4], sc2[4], se[4];
    const int w = tid >> 6, l = tid & 63;
    if (l == 0) { sd[w] = dice; sc2[w] = cnt; se[w] = ce_s; }
    __syncthreads();
    if (tid == 0) {
        const float D  = sd[0] + sd[1] + sd[2] + sd[3];
        const float Cn = sc2[0] + sc2[1] + sc2[2] + sc2[3];
        const float CE = (se[0] + se[1] + se[2] + se[3]) / fmaxf(Cn, 1.0f);
        out[0] = 0.4f * CE + 0.6f * (D / 176.f);
    }
}

extern "C" void kernel_launch(void* const* d_in, const int* in_sizes, int n_in,
                              void* d_out, int out_size, void* d_ws, size_t ws_size,
                              hipStream_t stream) {
    const float* pred = (const float*)d_in[0];
    const int*   tgt  = (const int*)d_in[1];
    float* ws = (float*)d_ws;

    (void)hipMemsetAsync(d_ws, 0, SLOTS * WS_PER_SLOT * sizeof(float), stream);
    seg_loss_main<<<2 * BLOCKS_PER_B, TPB, 0, stream>>>(pred, tgt, ws);
    seg_loss_final<<<1, TPB, 0, stream>>>(ws, (float*)d_out);
}